// Round 13
// baseline (181.213 us; speedup 1.0000x reference)
//
#include <hip/hip_runtime.h>
#include <math.h>

#define B_ 8
#define T_ 64
#define N_ 196
#define D_ 768
#define K_ 8
#define FEAT 40
#define EPSF 1e-6f

constexpr int BN = B_ * N_;                        // 1568
constexpr int ROWS = B_ * T_ * N_;                 // 100352
constexpr long long HSIZE = (long long)ROWS * D_;  // 77070336
constexpr int QPR = D_ / 4;                        // 192 float4 per row
constexpr unsigned RSTRIDE = (unsigned)N_ * QPR;   // 37632 v4f per t-step

typedef float v4f __attribute__((ext_vector_type(4)));

__device__ __forceinline__ float wredux(float v) {
#pragma unroll
    for (int off = 32; off > 0; off >>= 1)
        v += __shfl_xor(v, off, 64);
    return v;
}

__device__ __forceinline__ float dot4(v4f a, v4f b) {
    return a.x * b.x + a.y * b.y + a.z * b.z + a.w * b.w;
}

// W = softplus(W_raw) -> d_out tail;  beta_s = sigmoid(beta) -> ws
// (round-11 lesson: NEVER recompute softplus per block — 48M transcendentals)
__global__ __launch_bounds__(256) void k_wsp(const float* __restrict__ wraw,
                                             const float* __restrict__ beta,
                                             float* __restrict__ wout,
                                             float* __restrict__ beta_s) {
    int i = blockIdx.x * blockDim.x + threadIdx.x;
    if (i < FEAT * D_) {
        float xw = wraw[i];
        wout[i] = fmaxf(xw, 0.0f) + log1pf(expf(-fabsf(xw)));
    }
    if (i < D_) beta_s[i] = 1.0f / (1.0f + expf(-beta[i]));
}

// Fused, one block per (b,n), 256 threads = 4 waves.
// Phase A: LDS-staged x tiles, SINGLE-buffered (12 KB) — the register
// prefetch (R holds tile t+1 while computing tile t from LDS) provides the
// pipelining; the saved 12 KB lifts residency 3 -> ~8 blocks/CU
// (round-12 limiter: 30.7 KB LDS -> 3 resident blocks -> phase bubbles).
// launch_bounds(256,8): target 8 waves/EU; VGPR cap 64 (measured need: 56).
__global__ __launch_bounds__(256, 8)
void k_fused(const float* __restrict__ x,
             const float* __restrict__ mask,
             const float* __restrict__ pw,
             const float* __restrict__ wsp,
             const float* __restrict__ beta_s,
             float* __restrict__ h) {
    __shared__ v4f   xbuf[4][QPR];        // 12 KB x tile (single buffer)
    __shared__ float vpart[T_][K_ + 1];   // pad: odd stride, conflict-free
    __shared__ float sf[FEAT];
    __shared__ float ylds[D_];
    __shared__ float smask[T_];

    const int tid  = threadIdx.x;
    const int lane = tid & 63;
    const int w    = tid >> 6;
    const int bn   = blockIdx.x;
    const int b    = bn / N_;
    const int n    = bn - b * N_;

    // u-slice for this wave's two k's: 6 v4f = 24 VGPRs, loop-invariant
    v4f u[2][3];
#pragma unroll
    for (int kk = 0; kk < 2; kk++)
#pragma unroll
        for (int c = 0; c < 3; c++)
            u[kk][c] = *(const v4f*)(pw + (2 * w + kk) * D_ + c * 256 + lane * 4);

    if (tid < T_) smask[tid] = mask[(b * T_ + tid) * N_ + n];

    // ---- Phase A: 16 tiles x 4 rows; wave w stages row w of each tile ----
    const v4f* x4 = (const v4f*)x;
    const unsigned TSTRIDE = 4 * RSTRIDE;
    unsigned q = (unsigned)((b * T_ + w) * N_ + n) * QPR;
    v4f R0 = x4[q + lane], R1 = x4[q + 64 + lane], R2 = x4[q + 128 + lane];
#pragma unroll 1
    for (int tile = 0; tile < 16; ++tile) {
        // (A) previous tile's LDS reads complete -> safe to overwrite
        __syncthreads();
        xbuf[w][lane]       = R0;
        xbuf[w][64 + lane]  = R1;
        xbuf[w][128 + lane] = R2;
        if (tile < 15) {   // issue next tile's loads; land during compute
            q += TSTRIDE;
            R0 = x4[q + lane];
            R1 = x4[q + 64 + lane];
            R2 = x4[q + 128 + lane];
        }
        // (B) ds_writes visible
        __syncthreads();
#pragma unroll
        for (int r = 0; r < 4; ++r) {
            v4f c0 = xbuf[r][lane];
            v4f c1 = xbuf[r][64 + lane];
            v4f c2 = xbuf[r][128 + lane];
            float a0 = dot4(c0, u[0][0]) + dot4(c1, u[0][1]) + dot4(c2, u[0][2]);
            float a1 = dot4(c0, u[1][0]) + dot4(c1, u[1][1]) + dot4(c2, u[1][2]);
            a0 += __shfl_xor(a0, 1, 64);
            a1 += __shfl_xor(a1, 1, 64);
            float val = (lane & 1) ? a1 : a0;
            val += __shfl_xor(val, 2, 64);
            val += __shfl_xor(val, 4, 64);
            val += __shfl_xor(val, 8, 64);
            val += __shfl_xor(val, 16, 64);
            val += __shfl_xor(val, 32, 64);
            if (lane < 2) vpart[tile * 4 + r][2 * w + lane] = val;
        }
    }
    __syncthreads();

    // ---- Phase B: wave w owns k = w and k = w+4; lane = t ----
#pragma unroll
    for (int kk = 0; kk < 2; kk++) {
        const int k = w + kk * 4;
        float v = vpart[lane][k] * smask[lane];
        float s2  = wredux(v * v);
        float rms = sqrtf(s2 * (1.0f / T_) + EPSF);
        float vb  = 2.5f * tanhf(v / (rms + EPSF));
        const float PI = 3.14159265358979323846f;
        float ph = PI * ((float)lane + 0.5f) / (float)T_;
        float c1 = cosf(ph), c2 = cosf(2.0f * ph);
        float n1 = wredux(c1 * c1), n2 = wredux(c2 * c2);
        float S1 = wredux(vb), Sc1 = wredux(vb * c1);
        float Sc2 = wredux(vb * c2), Sq = wredux(vb * vb);
        if (lane == 0) {
            float* o = sf + k * 5;
            o[0] = S1 / (8.0f + EPSF);
            o[1] = Sc1 / (sqrtf(n1) + EPSF);
            o[2] = Sc2 / (sqrtf(n2) + EPSF);
            o[3] = S1 * (1.0f / T_);
            o[4] = sqrtf(Sq * (1.0f / T_) + EPSF);
        }
    }
    __syncthreads();

    // ---- Phase C: ylds[d] = beta_s[d] * sum_f sf[f]*wsp[f][d] (L2-hot) ----
    for (int d = tid; d < D_; d += 256) {
        float a0 = 0.f, a1 = 0.f;
#pragma unroll
        for (int f = 0; f < FEAT; f += 2) {
            a0 += sf[f]     * wsp[f * D_ + d];
            a1 += sf[f + 1] * wsp[(f + 1) * D_ + d];
        }
        ylds[d] = (a0 + a1) * beta_s[d];
    }
    __syncthreads();

    // ---- Phase D: rows t = w*16..w*16+15; x reload L3-hot; nt stores ----
    const v4f* y4 = (const v4f*)ylds;
    const v4f y0 = y4[lane], y1 = y4[64 + lane], y2 = y4[128 + lane];
    v4f* h4 = (v4f*)h;
    unsigned qD = (unsigned)((b * T_ + w * 16) * N_ + n) * QPR;
    v4f d0 = __builtin_nontemporal_load(x4 + qD + lane);
    v4f d1 = __builtin_nontemporal_load(x4 + qD + 64 + lane);
    v4f d2 = __builtin_nontemporal_load(x4 + qD + 128 + lane);
#pragma unroll 1
    for (int j = 0; j < 16; j++) {
        v4f c0 = d0, c1 = d1, c2 = d2;
        const unsigned qc = qD;
        if (j < 15) {
            qD += RSTRIDE;
            d0 = __builtin_nontemporal_load(x4 + qD + lane);
            d1 = __builtin_nontemporal_load(x4 + qD + 64 + lane);
            d2 = __builtin_nontemporal_load(x4 + qD + 128 + lane);
        }
        const float m = smask[w * 16 + j];
        __builtin_nontemporal_store(c0 + m * y0, h4 + qc + lane);
        __builtin_nontemporal_store(c1 + m * y1, h4 + qc + 64 + lane);
        __builtin_nontemporal_store(c2 + m * y2, h4 + qc + 128 + lane);
    }
}

extern "C" void kernel_launch(void* const* d_in, const int* in_sizes, int n_in,
                              void* d_out, int out_size, void* d_ws, size_t ws_size,
                              hipStream_t stream) {
    const float* x    = (const float*)d_in[0];
    const float* mask = (const float*)d_in[1];
    const float* pw   = (const float*)d_in[2];
    const float* wraw = (const float*)d_in[3];
    const float* beta = (const float*)d_in[4];

    float* h    = (float*)d_out;
    float* wout = h + HSIZE;
    float* beta_s = (float*)d_ws;   // [768]

    hipLaunchKernelGGL(k_wsp, dim3((FEAT * D_ + 255) / 256), dim3(256), 0, stream,
                       wraw, beta, wout, beta_s);
    hipLaunchKernelGGL(k_fused, dim3(BN), dim3(256), 0, stream,
                       x, mask, pw, wout, beta_s, h);
}